// Round 12
// baseline (53849.683 us; speedup 1.0000x reference)
//
#include <hip/hip_runtime.h>
#include <math.h>

#define BSZ 2048
#define MM  256
#define EE  128
#define HSS 512
#define HPP 256
#define NOWN 64
#define NBLK 129
#define LEADER 128
#define TPB 512
#define ROWS 4

typedef float f4 __attribute__((ext_vector_type(4)));

// ---- padded flag layout (1 flag per 128B line) ----
#define MSQ_IDX   0
#define ROWQ(g)   ((1+(g))*32)
#define SCQ(g)    ((65+(g))*32)
// float offsets:
#define OFF_ES    4160                  // [2][64] lines (value-as-flag, >0)
#define OFF_BD    8256                  // [64] lines, 4 floats (value-as-flag, >0)
#define OFF_PE    10304
#define OFF_R0    (OFF_PE + MM*EE)
#define OFF_W0    (OFF_R0 + BSZ)
#define OFF_MP    (OFF_W0 + BSZ*MM)     // [2][MM][EE]
#define OFF_SW    (OFF_MP + 2*MM*EE)    // [2][MM][MM]
#define OFF_EV    (OFF_SW + 2*MM*MM)    // [NOWN][EE]
#define OFF_CS    (OFF_EV + NOWN*EE)    // Wemb@Ws[0:128]: 4*HSS
#define OFF_CBS   (OFF_CS + 4*HSS)
#define OFF_CP    (OFF_CBS + HSS)       // Wemb@Wp1[0:128]: 4*HPP
#define OFF_CBP   (OFF_CP + 4*HPP)
#define OFF_MS2   (OFF_CBP + HPP)       // EE
#define OFF_BP    (OFF_MS2 + EE)        // NOWN*ROWS*EE

struct KParams {
  const float *state, *mem0, *Wemb, *bemb, *Wr1, *br1, *Wr2, *br2;
  const float *Ww1, *bw1, *Ww2, *bw2, *Ws, *bs, *Wa, *ba, *Wc, *bc;
  const float *Wp1, *bp1, *Wp2, *bp2;
  float *out;
  float *ws;
};

__device__ __forceinline__ float ldA(const float* p) {
  return __hip_atomic_load(p, __ATOMIC_RELAXED, __HIP_MEMORY_SCOPE_AGENT);
}
__device__ __forceinline__ void stA(float* p, float v) {
  __hip_atomic_store(p, v, __ATOMIC_RELAXED, __HIP_MEMORY_SCOPE_AGENT);
}
__device__ __forceinline__ unsigned ldAu(const unsigned* p) {
  return __hip_atomic_load(p, __ATOMIC_RELAXED, __HIP_MEMORY_SCOPE_AGENT);
}
__device__ __forceinline__ void stAu(unsigned* p, unsigned v) {
  __hip_atomic_store(p, v, __ATOMIC_RELAXED, __HIP_MEMORY_SCOPE_AGENT);
}

__device__ __forceinline__ void ldA4x8(const float* p, int strideF, f4* v) {
  const float *p1=p+strideF, *p2=p+2*strideF, *p3=p+3*strideF,
              *p4=p+4*strideF, *p5=p+5*strideF, *p6=p+6*strideF, *p7=p+7*strideF;
  asm volatile(
    "global_load_dwordx4 %0, %8, off sc0 sc1\n\t"
    "global_load_dwordx4 %1, %9, off sc0 sc1\n\t"
    "global_load_dwordx4 %2, %10, off sc0 sc1\n\t"
    "global_load_dwordx4 %3, %11, off sc0 sc1\n\t"
    "global_load_dwordx4 %4, %12, off sc0 sc1\n\t"
    "global_load_dwordx4 %5, %13, off sc0 sc1\n\t"
    "global_load_dwordx4 %6, %14, off sc0 sc1\n\t"
    "global_load_dwordx4 %7, %15, off sc0 sc1\n\t"
    "s_waitcnt vmcnt(0)"
    : "=&v"(v[0]), "=&v"(v[1]), "=&v"(v[2]), "=&v"(v[3]),
      "=&v"(v[4]), "=&v"(v[5]), "=&v"(v[6]), "=&v"(v[7])
    : "v"(p), "v"(p1), "v"(p2), "v"(p3), "v"(p4), "v"(p5), "v"(p6), "v"(p7)
    : "memory");
}
__device__ __forceinline__ void ldA4x4(const float* p, int strideF, f4* v) {
  const float *p1=p+strideF, *p2=p+2*strideF, *p3=p+3*strideF;
  asm volatile(
    "global_load_dwordx4 %0, %4, off sc0 sc1\n\t"
    "global_load_dwordx4 %1, %5, off sc0 sc1\n\t"
    "global_load_dwordx4 %2, %6, off sc0 sc1\n\t"
    "global_load_dwordx4 %3, %7, off sc0 sc1\n\t"
    "s_waitcnt vmcnt(0)"
    : "=&v"(v[0]), "=&v"(v[1]), "=&v"(v[2]), "=&v"(v[3])
    : "v"(p), "v"(p1), "v"(p2), "v"(p3)
    : "memory");
}
__device__ __forceinline__ f4 ldA4(const float* p) {
  f4 r;
  asm volatile("global_load_dwordx4 %0, %1, off sc0 sc1\n\ts_waitcnt vmcnt(0)"
    : "=&v"(r) : "v"(p) : "memory");
  return r;
}

__device__ __forceinline__ void drainSync() {
  asm volatile("s_waitcnt vmcnt(0)" ::: "memory");
  __syncthreads();
}

__device__ __forceinline__ float brs(float v, float* s8, int tid) {
  for (int o = 32; o > 0; o >>= 1) v += __shfl_down(v, o, 64);
  __syncthreads();
  if ((tid & 63) == 0) s8[tid >> 6] = v;
  __syncthreads();
  float r = s8[0]+s8[1]+s8[2]+s8[3]+s8[4]+s8[5]+s8[6]+s8[7];
  __syncthreads();
  return r;
}

template<int N>
__device__ __forceinline__ void brsN(float* v, float* sred, int tid) {
  #pragma unroll
  for (int k = 0; k < N; ++k)
    for (int o = 32; o > 0; o >>= 1) v[k] += __shfl_down(v[k], o, 64);
  __syncthreads();
  if ((tid & 63) == 0) {
    const int w = tid >> 6;
    #pragma unroll
    for (int k = 0; k < N; ++k) sred[k*8 + w] = v[k];
  }
  __syncthreads();
  #pragma unroll
  for (int k = 0; k < N; ++k) {
    float s = sred[k*8 + 0];
    #pragma unroll
    for (int w = 1; w < 8; ++w) s += sred[k*8 + w];
    v[k] = s;
  }
  __syncthreads();
}

__global__ __launch_bounds__(TPB, 2)   // 2 waves/EU => 1 block/CU => 256 VGPR budget
void toyac_kernel(KParams p) {
  const int g = blockIdx.x;
  const int tid = threadIdx.x;
  float* ws = p.ws;
  unsigned* bar = (unsigned*)p.ws;
  const int isOwner = (g < NOWN);
  const int og = (g >= NOWN && g < LEADER) ? (g - NOWN) : g;
  const int c0 = ROWS * ((g < NOWN) ? g : og);

  __shared__ float sBuf[8192];
  __shared__ float sH4[ROWS][HSS];   // helper hidden; alias sEv in dBulk
  __shared__ float sX[ROWS][EE];
  __shared__ float sP[ROWS][EE];
  __shared__ float sPE[ROWS][EE];
  __shared__ float sHv[HSS];         // P0b
  __shared__ float sMS[EE];
  __shared__ float sMS2[EE];
  __shared__ float sSE[EE];
  __shared__ float sP1[HPP];
  __shared__ float sD[ROWS];
  __shared__ float sR48[48];
  __shared__ float s8[8];
  __shared__ float sRed[16];
  __shared__ float sSm[40];

  float (*sEv)[MM] = (float(*)[MM])sH4;

  const int hq = (tid & 127) * 4;
  const int eg4 = tid >> 7;

  // ================= P0a =================
  if (isOwner) {
    const int e = tid & 127, r = tid >> 7, c = c0 + r;
    double dv = exp(-(double)(2*(e>>1)) * log(10000.0) / 128.0);
    double arg = (double)c * dv;
    float pev = ((e & 1) == 0) ? (float)sin(arg) : (float)cos(arg);
    sPE[r][e] = pev;
    float m0v = p.mem0[(size_t)c*EE + e] + pev;
    stA(ws + OFF_MP + (size_t)c*EE + e, m0v);
    sX[r][e] = m0v;
  } else if (g == LEADER) {
    for (int jj = tid; jj < HSS; jj += TPB) {
      float a0=0.f,a1=0.f,a2=0.f,a3=0.f,cb=0.f;
      for (int e = 0; e < EE; ++e) {
        float wv = p.Ws[(size_t)e*HSS + jj];
        a0 += p.Wemb[e]*wv; a1 += p.Wemb[EE+e]*wv;
        a2 += p.Wemb[2*EE+e]*wv; a3 += p.Wemb[3*EE+e]*wv;
        cb += p.bemb[e]*wv;
      }
      ws[OFF_CS + jj] = a0; ws[OFF_CS + HSS + jj] = a1;
      ws[OFF_CS + 2*HSS + jj] = a2; ws[OFF_CS + 3*HSS + jj] = a3;
      ws[OFF_CBS + jj] = cb;
    }
    if (tid < HPP) {
      int k = tid;
      float a0=0.f,a1=0.f,a2=0.f,a3=0.f,cb=0.f;
      for (int e = 0; e < EE; ++e) {
        float wv = p.Wp1[(size_t)e*HPP + k];
        a0 += p.Wemb[e]*wv; a1 += p.Wemb[EE+e]*wv;
        a2 += p.Wemb[2*EE+e]*wv; a3 += p.Wemb[3*EE+e]*wv;
        cb += p.bemb[e]*wv;
      }
      ws[OFF_CP + k] = a0; ws[OFF_CP + HPP + k] = a1;
      ws[OFF_CP + 2*HPP + k] = a2; ws[OFF_CP + 3*HPP + k] = a3;
      ws[OFF_CBP + k] = cb;
    }
  }

  // ================= P0b: per-step R0, W0 (striped over 129 blocks) =================
  for (int t = g; t < BSZ; t += NBLK) {
    __syncthreads();
    if (tid < EE) {
      const float* st = p.state + (size_t)t*4;
      sSE[tid] = st[0]*p.Wemb[tid] + st[1]*p.Wemb[EE+tid]
               + st[2]*p.Wemb[2*EE+tid] + st[3]*p.Wemb[3*EE+tid] + p.bemb[tid];
    }
    __syncthreads();
    { // reader score r0
      f4 a = {0.f,0.f,0.f,0.f};
      const float* base = p.Wr1 + (size_t)(eg4*32)*HSS + hq;
      for (int i = 0; i < 32; ++i)
        a += sSE[eg4*32 + i] * (*(const f4*)(base + (size_t)i*HSS));
      *(f4*)(sBuf + (size_t)eg4*HSS + hq) = a;
      __syncthreads();
      int h = tid;
      float hid = sBuf[h] + sBuf[HSS+h] + sBuf[2*HSS+h] + sBuf[3*HSS+h] + p.br1[h];
      float v = fmaxf(hid, 0.f) * p.Wr2[h];
      float sc = brs(v, s8, tid);
      if (tid == 0) stA(ws + OFF_R0 + t, sc + p.br2[0]);
      __syncthreads();
    }
    { // writer row0
      f4 a = {0.f,0.f,0.f,0.f};
      const float* base = p.Ww1 + (size_t)(eg4*32)*HSS + hq;
      for (int i = 0; i < 32; ++i)
        a += sSE[eg4*32 + i] * (*(const f4*)(base + (size_t)i*HSS));
      *(f4*)(sBuf + (size_t)eg4*HSS + hq) = a;
      __syncthreads();
      int h = tid;
      sHv[h] = fmaxf(sBuf[h] + sBuf[HSS+h] + sBuf[2*HSS+h] + sBuf[3*HSS+h] + p.bw1[h], 0.f);
      __syncthreads();
      const int cq = (tid & 63) * 4, hg = tid >> 6;
      f4 q = {0.f,0.f,0.f,0.f};
      const float* b2 = p.Ww2 + (size_t)(hg*64)*MM + cq;
      for (int i = 0; i < 64; ++i)
        q += sHv[hg*64 + i] * (*(const f4*)(b2 + (size_t)i*MM));
      *(f4*)(sBuf + (size_t)hg*MM + cq) = q;
      __syncthreads();
      if (tid < MM) {
        float s = 0.f;
        #pragma unroll
        for (int k = 0; k < 8; ++k) s += sBuf[(size_t)k*MM + tid];
        stA(ws + OFF_W0 + (size_t)t*MM + tid, s + p.bw2[tid]);
      }
      __syncthreads();
    }
  }

  auto ww2pass = [&](float* swdst) {
    const int cq = (tid & 63) * 4, hg = tid >> 6;
    f4 q0={0.f,0.f,0.f,0.f},q1=q0,q2=q0,q3=q0;
    const float* b2 = p.Ww2 + (size_t)(hg*64)*MM + cq;
    for (int i = 0; i < 64; ++i) {
      f4 w = *(const f4*)(b2 + (size_t)i*MM);
      int h = hg*64 + i;
      q0 += sH4[0][h]*w; q1 += sH4[1][h]*w; q2 += sH4[2][h]*w; q3 += sH4[3][h]*w;
    }
    *(f4*)(sBuf + ((size_t)hg*ROWS + 0)*MM + cq) = q0;
    *(f4*)(sBuf + ((size_t)hg*ROWS + 1)*MM + cq) = q1;
    *(f4*)(sBuf + ((size_t)hg*ROWS + 2)*MM + cq) = q2;
    *(f4*)(sBuf + ((size_t)hg*ROWS + 3)*MM + cq) = q3;
    __syncthreads();
    {
      const int col = tid & 255, rp = tid >> 8;
      #pragma unroll
      for (int rr = 0; rr < 2; ++rr) {
        int r = rp*2 + rr;
        float s = 0.f;
        #pragma unroll
        for (int k = 0; k < 8; ++k) s += sBuf[((size_t)k*ROWS + r)*MM + col];
        stA(swdst + (size_t)(c0 + r)*MM + col, s + p.bw2[col]);
      }
    }
  };

  auto stageC = [&](float* swdst) {
    {
      f4 a0={0.f,0.f,0.f,0.f},a1=a0,a2=a0,a3=a0;
      const float* base = p.Ww1 + (size_t)(eg4*32)*HSS + hq;
      for (int i = 0; i < 32; ++i) {
        f4 w = *(const f4*)(base + (size_t)i*HSS);
        int e = eg4*32 + i;
        a0 += sX[0][e]*w; a1 += sX[1][e]*w; a2 += sX[2][e]*w; a3 += sX[3][e]*w;
      }
      *(f4*)(sBuf + ((size_t)eg4*ROWS + 0)*HSS + hq) = a0;
      *(f4*)(sBuf + ((size_t)eg4*ROWS + 1)*HSS + hq) = a1;
      *(f4*)(sBuf + ((size_t)eg4*ROWS + 2)*HSS + hq) = a2;
      *(f4*)(sBuf + ((size_t)eg4*ROWS + 3)*HSS + hq) = a3;
    }
    __syncthreads();
    {
      int h = tid;
      float b = p.bw1[h];
      #pragma unroll
      for (int r = 0; r < ROWS; ++r)
        sH4[r][h] = fmaxf(sBuf[(0*ROWS+r)*HSS+h] + sBuf[(1*ROWS+r)*HSS+h]
                        + sBuf[(2*ROWS+r)*HSS+h] + sBuf[(3*ROWS+r)*HSS+h] + b, 0.f);
    }
    __syncthreads();
    ww2pass(swdst);
  };

  auto dBulkH = [&](int tt) {
    float* swc = ws + OFF_SW + (size_t)(tt&1)*MM*MM;
    float* mpc = ws + OFF_MP + (size_t)(tt&1)*MM*EE;
    float ex[ROWS] = {0.f,0.f,0.f,0.f};
    if (tid < MM) {
      f4 s = ldA4(swc + (size_t)tid*MM + c0);
      #pragma unroll
      for (int r = 0; r < ROWS; ++r) { ex[r] = expf(s[r]); sEv[r][tid] = ex[r]; }
    }
    brsN<ROWS>(ex, sR48, tid);
    if (tid == 0) { sD[0]=ex[0]; sD[1]=ex[1]; sD[2]=ex[2]; sD[3]=ex[3]; }
    {
      const int e4 = (tid & 31) * 4, rg = tid >> 5;
      f4 a0={0.f,0.f,0.f,0.f},a1=a0,a2=a0,a3=a0;
      const float* base = mpc + (size_t)(rg*16)*EE + e4;
      f4 vv[8];
      ldA4x8(base, EE, vv);
      #pragma unroll
      for (int i = 0; i < 8; ++i) {
        int r0 = rg*16 + i;
        a0 += sEv[0][r0]*vv[i]; a1 += sEv[1][r0]*vv[i];
        a2 += sEv[2][r0]*vv[i]; a3 += sEv[3][r0]*vv[i];
      }
      ldA4x8(base + 8*EE, EE, vv);
      #pragma unroll
      for (int i = 0; i < 8; ++i) {
        int r0 = rg*16 + 8 + i;
        a0 += sEv[0][r0]*vv[i]; a1 += sEv[1][r0]*vv[i];
        a2 += sEv[2][r0]*vv[i]; a3 += sEv[3][r0]*vv[i];
      }
      *(f4*)(sBuf + ((size_t)0*16 + rg)*EE + e4) = a0;
      *(f4*)(sBuf + ((size_t)1*16 + rg)*EE + e4) = a1;
      *(f4*)(sBuf + ((size_t)2*16 + rg)*EE + e4) = a2;
      *(f4*)(sBuf + ((size_t)3*16 + rg)*EE + e4) = a3;
    }
    __syncthreads();
    {
      const int e = tid & 127, r = tid >> 7;
      float s = 0.f;
      #pragma unroll
      for (int q = 0; q < 16; ++q) s += sBuf[((size_t)r*16 + q)*EE + e];
      stA(ws + OFF_BP + ((size_t)og*ROWS + r)*EE + e, s);
    }
  };

  // ================= main =================
  if (g == LEADER) {
    // ---- register-cached weights (256-VGPR budget via launch_bounds(512,2)) ----
    float wsReg[EE];     // Ws[128+e][tid]
    #pragma unroll
    for (int e = 0; e < EE; ++e) wsReg[e] = p.Ws[(size_t)(EE + e)*HSS + tid];
    float wp2Reg[64];    // Wp2[kq*64+i][tid&127]
    const int ecol = tid & 127, kq = tid >> 7;
    #pragma unroll
    for (int i = 0; i < 64; ++i) wp2Reg[i] = p.Wp2[(size_t)(kq*64 + i)*EE + ecol];

    for (int t = 0; t < BSZ; ++t) {
      float er0 = expf(ldA(ws + OFF_R0 + t));
      float v = 0.f;
      if (tid < NOWN) {
        float* es = ws + OFF_ES + (size_t)((t&1)*NOWN + tid)*32;
        do { v = ldA(es); } while (v == 0.f);
        stA(es, 0.f);
      }
      float invd = 1.f / (er0 + brs(v, s8, tid));
      {
        const int e4 = (tid & 31) * 4, qg = tid >> 5;
        f4 vv[4];
        ldA4x4(ws + OFF_EV + (size_t)(qg*4)*EE + e4, EE, vv);
        f4 acc = vv[0]+vv[1]+vv[2]+vv[3];
        *(f4*)(sBuf + (size_t)qg*EE + e4) = acc;
      }
      __syncthreads();
      {
        const float* st = p.state + (size_t)t*4;
        const float s0 = st[0], s1 = st[1], s2 = st[2], s3 = st[3];
        if (tid < EE) {
          float se = s0*p.Wemb[tid] + s1*p.Wemb[EE+tid]
                   + s2*p.Wemb[2*EE+tid] + s3*p.Wemb[3*EE+tid] + p.bemb[tid];
          float s = 0.f;
          #pragma unroll
          for (int q = 0; q < 16; ++q) s += sBuf[(size_t)q*EE + tid];
          sMS[tid] = (er0*se + s) * invd;
        }
        __syncthreads();
        // trunk hidden: pure register FMA
        float hv;
        {
          float acc = 0.f;
          #pragma unroll
          for (int e = 0; e < EE; ++e) acc += sMS[e] * wsReg[e];
          const float* cs = ws + OFF_CS;
          float sh0 = s0*cs[tid] + s1*cs[HSS+tid] + s2*cs[2*HSS+tid] + s3*cs[3*HSS+tid]
                    + ws[OFF_CBS + tid];
          hv = fmaxf(acc + sh0 + p.bs[tid], 0.f);
        }
        {
          float pa[6];
          #pragma unroll
          for (int aa = 0; aa < 5; ++aa) pa[aa] = hv * p.Wa[(size_t)tid*5 + aa];
          pa[5] = hv * p.Wc[tid];
          brsN<6>(pa, sR48, tid);
          if (tid == 0) {
            float l0=pa[0]+p.ba[0], l1=pa[1]+p.ba[1], l2=pa[2]+p.ba[2];
            float l3=pa[3]+p.ba[3], l4=pa[4]+p.ba[4];
            float mx = fmaxf(fmaxf(fmaxf(l0,l1),fmaxf(l2,l3)), l4);
            float e0=expf(l0-mx),e1=expf(l1-mx),e2=expf(l2-mx),e3=expf(l3-mx),e4v=expf(l4-mx);
            float is = 1.f/(e0+e1+e2+e3+e4v);
            float p0=e0*is,p1=e1*is,p2=e2*is,p3=e3*is,p4=e4v*is;
            p.out[(size_t)t*5+0]=p0; p.out[(size_t)t*5+1]=p1; p.out[(size_t)t*5+2]=p2;
            p.out[(size_t)t*5+3]=p3; p.out[(size_t)t*5+4]=p4;
            float val = pa[5] + p.bc[0];
            p.out[(size_t)BSZ*5 + t] = val;
            sSm[1]=p0; sSm[2]=p1; sSm[3]=p2; sSm[4]=p3; sSm[5]=p4; sSm[6]=val;
          }
          __syncthreads();
        }
        { // p1 stream (Wp1 mem-half, still streamed)
          const int cq = (tid & 63) * 4, eg8 = tid >> 6;
          f4 a = {0.f,0.f,0.f,0.f};
          const float* base = p.Wp1 + (size_t)(EE + eg8*16)*HPP + cq;
          for (int i = 0; i < 16; ++i)
            a += sMS[eg8*16 + i] * (*(const f4*)(base + (size_t)i*HPP));
          *(f4*)(sBuf + (size_t)eg8*HPP + cq) = a;
        }
        __syncthreads();
        if (tid < HPP) {
          const float* cp = ws + OFF_CP;
          float acc = s0*cp[tid] + s1*cp[HPP+tid] + s2*cp[2*HPP+tid] + s3*cp[3*HPP+tid]
                    + ws[OFF_CBP + tid] + p.bp1[tid];
          #pragma unroll
          for (int q = 0; q < 8; ++q) acc += sBuf[(size_t)q*HPP + tid];
          #pragma unroll
          for (int aa = 0; aa < 5; ++aa) acc += sSm[1+aa] * p.Wp1[(size_t)(2*EE+aa)*HPP + tid];
          acc += sSm[6] * p.Wp1[(size_t)(2*EE+5)*HPP + tid];
          sP1[tid] = fmaxf(acc, 0.f);
        }
        __syncthreads();
        { // ms2: register FMA (4 thread-groups over k, LDS combine)
          float a2 = 0.f;
          #pragma unroll
          for (int i = 0; i < 64; ++i) a2 += sP1[kq*64 + i] * wp2Reg[i];
          sBuf[(size_t)kq*EE + ecol] = a2;
        }
        __syncthreads();
        if (tid < EE) {
          float s = sBuf[tid] + sBuf[EE+tid] + sBuf[2*EE+tid] + sBuf[3*EE+tid];
          stA(ws + OFF_MS2 + tid, s + p.bp2[tid]);
        }
      }
      drainSync();
      if (tid == 0) stAu(&bar[MSQ_IDX], (unsigned)(t+1));
    }
  } else if (isOwner) {
    // -------- OWNER --------
    const f4 wcol = *(const f4*)(p.Ww2 + (size_t)tid*MM + c0);
    const float rBw1v = p.bw1[tid];
    // register-cached Wr1 column tid
    float wrReg[EE];
    #pragma unroll
    for (int e = 0; e < EE; ++e) wrReg[e] = p.Wr1[(size_t)e*HSS + tid];

    auto stageAreg = [&](float* esSumOut) {
      float h0=0.f,h1=0.f,h2=0.f,h3=0.f;
      #pragma unroll
      for (int e = 0; e < EE; ++e) {
        float w = wrReg[e];
        h0 += sX[0][e]*w; h1 += sX[1][e]*w; h2 += sX[2][e]*w; h3 += sX[3][e]*w;
      }
      float b = p.br1[tid], wr = p.Wr2[tid];
      float sc[ROWS] = { fmaxf(h0+b,0.f)*wr, fmaxf(h1+b,0.f)*wr,
                         fmaxf(h2+b,0.f)*wr, fmaxf(h3+b,0.f)*wr };
      brsN<ROWS>(sc, sR48, tid);
      float es[ROWS];
      #pragma unroll
      for (int r = 0; r < ROWS; ++r) es[r] = expf(sc[r] + p.br2[0]);
      if (tid < EE) {
        float v = es[0]*sX[0][tid] + es[1]*sX[1][tid] + es[2]*sX[2][tid] + es[3]*sX[3][tid];
        stA(ws + OFF_EV + (size_t)g*EE + tid, v);
      }
      *esSumOut = es[0]+es[1]+es[2]+es[3];
    };

    drainSync();
    if (tid == 0) stAu(&bar[ROWQ(g)], 1u);     // rows(0) ready
    float esSum;
    stageAreg(&esSum);
    drainSync();
    if (tid == 0) stA(ws + OFF_ES + (size_t)g*32, esSum);   // ES(0), parity 0

    for (int t = 0; t < BSZ-1; ++t) {
      // flag-independent precompute
      if (tid < EE) {
        const float* st = p.state + (size_t)t*4;
        sSE[tid] = st[0]*p.Wemb[tid] + st[1]*p.Wemb[EE+tid]
                 + st[2]*p.Wemb[2*EE+tid] + st[3]*p.Wemb[3*EE+tid] + p.bemb[tid];
      }
      if (tid == 0) {
        f4 w0 = ldA4(ws + OFF_W0 + (size_t)t*MM + c0);
        sSm[8]=expf(w0.x); sSm[9]=expf(w0.y); sSm[10]=expf(w0.z); sSm[11]=expf(w0.w);
      }
      // wait ms2(t) — busy poll
      if (tid == 0) { while (ldAu(&bar[MSQ_IDX]) < (unsigned)(t+1)) {} }
      __syncthreads();
      if (tid < EE) sMS2[tid] = ldA(ws + OFF_MS2 + tid);
      // BD poll (value-as-flag) + consume + reset
      if (tid == 0) {
        float* bd = ws + OFF_BD + (size_t)g*32;
        float x,y,z,w;
        do { x=ldA(bd); y=ldA(bd+1); z=ldA(bd+2); w=ldA(bd+3); }
        while (x==0.f || y==0.f || z==0.f || w==0.f);
        sD[0]=x; sD[1]=y; sD[2]=z; sD[3]=w;
        stA(bd,0.f); stA(bd+1,0.f); stA(bd+2,0.f); stA(bd+3,0.f);
      }
      __syncthreads();
      { // BP read
        const int e = tid & 127, r = tid >> 7;
        sP[r][e] = ldA(ws + OFF_BP + ((size_t)g*ROWS + r)*EE + e);
      }
      // hms = relu(ms2 @ Ww1 + bw1) (streamed)
      {
        f4 a = {0.f,0.f,0.f,0.f};
        const float* base = p.Ww1 + (size_t)(eg4*32)*HSS + hq;
        for (int i = 0; i < 32; ++i)
          a += sMS2[eg4*32 + i] * (*(const f4*)(base + (size_t)i*HSS));
        *(f4*)(sBuf + (size_t)eg4*HSS + hq) = a;
      }
      __syncthreads();
      float hm = fmaxf(sBuf[tid] + sBuf[HSS+tid] + sBuf[2*HSS+tid] + sBuf[3*HSS+tid]
                       + rBw1v, 0.f);
      __syncthreads();
      float swv[ROWS] = { hm*wcol.x, hm*wcol.y, hm*wcol.z, hm*wcol.w };
      brsN<ROWS>(swv, sR48, tid);
      // dFinish
      {
        const int e = tid & 127, r = tid >> 7;
        float ew1 = expf(swv[r] + p.bw2[c0+r]);
        float ew0 = sSm[8+r];
        float inv = 1.f / (sD[r] + ew0 + ew1);
        float x = (sP[r][e] + ew0*sSE[e] + ew1*sMS2[e]) * inv;
        float mn = x, mx = x;
        #pragma unroll
        for (int o = 1; o < 64; o <<= 1) {
          mn = fminf(mn, __shfl_xor(mn, o, 64));
          mx = fmaxf(mx, __shfl_xor(mx, o, 64));
        }
        if ((tid & 63) == 0) { sRed[(tid>>6)*2] = mn; sRed[(tid>>6)*2+1] = mx; }
        __syncthreads();
        mn = fminf(sRed[4*r], sRed[4*r+2]);
        mx = fmaxf(sRed[4*r+1], sRed[4*r+3]);
        float k = 1.f / (mx - mn);
        float xr = (x - mn) * k + sPE[r][e];
        stA(ws + OFF_MP + (size_t)((t+1)&1)*MM*EE + (size_t)(c0+r)*EE + e, xr);
        sX[r][e] = xr;
      }
      drainSync();
      if (tid == 0) stAu(&bar[ROWQ(g)], (unsigned)(t+2));  // rows(t+1)
      // stageA(t+1) from registers
      stageAreg(&esSum);
      drainSync();
      if (tid == 0) stA(ws + OFF_ES + (size_t)(((t+1)&1)*NOWN + g)*32, esSum);
    }
  } else {
    // -------- HELPER --------
    for (int t = 0; t < BSZ-1; ++t) {
      if (tid == 0) {
        while (ldAu(&bar[ROWQ(og)]) < (unsigned)(t+1)) __builtin_amdgcn_s_sleep(2);
      }
      __syncthreads();
      {
        const int e = tid & 127, r = tid >> 7;
        sX[r][e] = ldA(ws + OFF_MP + (size_t)(t&1)*MM*EE + (size_t)(c0+r)*EE + e);
      }
      __syncthreads();
      stageC(ws + OFF_SW + (size_t)(t&1)*MM*MM);
      drainSync();
      if (tid == 0) stAu(&bar[SCQ(og)], (unsigned)(t+1));
      if (tid < 64) {
        while (ldAu(&bar[SCQ(tid)]) < (unsigned)(t+1)) __builtin_amdgcn_s_sleep(2);
      } else if (tid < 128) {
        while (ldAu(&bar[ROWQ(tid-64)]) < (unsigned)(t+1)) __builtin_amdgcn_s_sleep(2);
      }
      __syncthreads();
      dBulkH(t);
      drainSync();
      if (tid == 0) {
        float* bd = ws + OFF_BD + (size_t)og*32;
        stA(bd,   sD[0]); stA(bd+1, sD[1]);
        stA(bd+2, sD[2]); stA(bd+3, sD[3]);
      }
    }
  }
}

extern "C" void kernel_launch(void* const* d_in, const int* in_sizes, int n_in,
                              void* d_out, int out_size, void* d_ws, size_t ws_size,
                              hipStream_t stream) {
  hipMemsetAsync(d_ws, 0, OFF_PE * 4, stream);
  KParams kp;
  kp.state = (const float*)d_in[0];
  kp.mem0  = (const float*)d_in[1];
  kp.Wemb  = (const float*)d_in[2];
  kp.bemb  = (const float*)d_in[3];
  kp.Wr1   = (const float*)d_in[4];
  kp.br1   = (const float*)d_in[5];
  kp.Wr2   = (const float*)d_in[6];
  kp.br2   = (const float*)d_in[7];
  kp.Ww1   = (const float*)d_in[8];
  kp.bw1   = (const float*)d_in[9];
  kp.Ww2   = (const float*)d_in[10];
  kp.bw2   = (const float*)d_in[11];
  kp.Ws    = (const float*)d_in[12];
  kp.bs    = (const float*)d_in[13];
  kp.Wa    = (const float*)d_in[14];
  kp.ba    = (const float*)d_in[15];
  kp.Wc    = (const float*)d_in[16];
  kp.bc    = (const float*)d_in[17];
  kp.Wp1   = (const float*)d_in[18];
  kp.bp1   = (const float*)d_in[19];
  kp.Wp2   = (const float*)d_in[20];
  kp.bp2   = (const float*)d_in[21];
  kp.out   = (float*)d_out;
  kp.ws    = (float*)d_ws;
  toyac_kernel<<<dim3(NBLK), dim3(TPB), 0, stream>>>(kp);
}

// Round 13
// 50715.359 us; speedup vs baseline: 1.0618x; 1.0618x over previous
//
#include <hip/hip_runtime.h>
#include <math.h>

#define BSZ 2048
#define MM  256
#define EE  128
#define HSS 512
#define HPP 256
#define NOWN 64
#define NBLK 129
#define LEADER 128
#define TPB 512
#define ROWS 4

typedef float f4 __attribute__((ext_vector_type(4)));

// ---- padded flag layout (1 flag per 128B line) ----
#define MSQ_IDX   0
#define ROWQ(g)   ((1+(g))*32)
#define SCQ(g)    ((65+(g))*32)
#define HMSQ_IDX  4128                  // line 129
// float offsets:
#define OFF_ES    4160                  // [2][64] lines (value-as-flag, >0)
#define OFF_BD    8256                  // [64] lines, 4 floats (value-as-flag, >0)
#define OFF_PE    10304
#define OFF_R0    (OFF_PE + MM*EE)
#define OFF_W0    (OFF_R0 + BSZ)
#define OFF_MP    (OFF_W0 + BSZ*MM)     // [2][MM][EE]
#define OFF_SW    (OFF_MP + 2*MM*EE)    // [2][MM][MM]
#define OFF_EV    (OFF_SW + 2*MM*MM)    // [NOWN][EE]
#define OFF_CS    (OFF_EV + NOWN*EE)    // Wemb@Ws[0:128]: 4*HSS
#define OFF_CBS   (OFF_CS + 4*HSS)
#define OFF_CP    (OFF_CBS + HSS)       // Wemb@Wp1[0:128]: 4*HPP
#define OFF_CBP   (OFF_CP + 4*HPP)
#define OFF_MS2   (OFF_CBP + HPP)       // EE
#define OFF_HMS   (OFF_MS2 + EE)        // HSS (leader-computed hms)
#define OFF_BP    (OFF_HMS + HSS)       // NOWN*ROWS*EE

struct KParams {
  const float *state, *mem0, *Wemb, *bemb, *Wr1, *br1, *Wr2, *br2;
  const float *Ww1, *bw1, *Ww2, *bw2, *Ws, *bs, *Wa, *ba, *Wc, *bc;
  const float *Wp1, *bp1, *Wp2, *bp2;
  float *out;
  float *ws;
};

__device__ __forceinline__ float ldA(const float* p) {
  return __hip_atomic_load(p, __ATOMIC_RELAXED, __HIP_MEMORY_SCOPE_AGENT);
}
__device__ __forceinline__ void stA(float* p, float v) {
  __hip_atomic_store(p, v, __ATOMIC_RELAXED, __HIP_MEMORY_SCOPE_AGENT);
}
__device__ __forceinline__ unsigned ldAu(const unsigned* p) {
  return __hip_atomic_load(p, __ATOMIC_RELAXED, __HIP_MEMORY_SCOPE_AGENT);
}
__device__ __forceinline__ void stAu(unsigned* p, unsigned v) {
  __hip_atomic_store(p, v, __ATOMIC_RELAXED, __HIP_MEMORY_SCOPE_AGENT);
}

__device__ __forceinline__ void ldA4x8(const float* p, int strideF, f4* v) {
  const float *p1=p+strideF, *p2=p+2*strideF, *p3=p+3*strideF,
              *p4=p+4*strideF, *p5=p+5*strideF, *p6=p+6*strideF, *p7=p+7*strideF;
  asm volatile(
    "global_load_dwordx4 %0, %8, off sc0 sc1\n\t"
    "global_load_dwordx4 %1, %9, off sc0 sc1\n\t"
    "global_load_dwordx4 %2, %10, off sc0 sc1\n\t"
    "global_load_dwordx4 %3, %11, off sc0 sc1\n\t"
    "global_load_dwordx4 %4, %12, off sc0 sc1\n\t"
    "global_load_dwordx4 %5, %13, off sc0 sc1\n\t"
    "global_load_dwordx4 %6, %14, off sc0 sc1\n\t"
    "global_load_dwordx4 %7, %15, off sc0 sc1\n\t"
    "s_waitcnt vmcnt(0)"
    : "=&v"(v[0]), "=&v"(v[1]), "=&v"(v[2]), "=&v"(v[3]),
      "=&v"(v[4]), "=&v"(v[5]), "=&v"(v[6]), "=&v"(v[7])
    : "v"(p), "v"(p1), "v"(p2), "v"(p3), "v"(p4), "v"(p5), "v"(p6), "v"(p7)
    : "memory");
}
__device__ __forceinline__ void ldA4x4(const float* p, int strideF, f4* v) {
  const float *p1=p+strideF, *p2=p+2*strideF, *p3=p+3*strideF;
  asm volatile(
    "global_load_dwordx4 %0, %4, off sc0 sc1\n\t"
    "global_load_dwordx4 %1, %5, off sc0 sc1\n\t"
    "global_load_dwordx4 %2, %6, off sc0 sc1\n\t"
    "global_load_dwordx4 %3, %7, off sc0 sc1\n\t"
    "s_waitcnt vmcnt(0)"
    : "=&v"(v[0]), "=&v"(v[1]), "=&v"(v[2]), "=&v"(v[3])
    : "v"(p), "v"(p1), "v"(p2), "v"(p3)
    : "memory");
}
__device__ __forceinline__ f4 ldA4(const float* p) {
  f4 r;
  asm volatile("global_load_dwordx4 %0, %1, off sc0 sc1\n\ts_waitcnt vmcnt(0)"
    : "=&v"(r) : "v"(p) : "memory");
  return r;
}

__device__ __forceinline__ void drainSync() {
  asm volatile("s_waitcnt vmcnt(0)" ::: "memory");
  __syncthreads();
}

__device__ __forceinline__ float brs(float v, float* s8, int tid) {
  for (int o = 32; o > 0; o >>= 1) v += __shfl_down(v, o, 64);
  __syncthreads();
  if ((tid & 63) == 0) s8[tid >> 6] = v;
  __syncthreads();
  float r = s8[0]+s8[1]+s8[2]+s8[3]+s8[4]+s8[5]+s8[6]+s8[7];
  __syncthreads();
  return r;
}

template<int N>
__device__ __forceinline__ void brsN(float* v, float* sred, int tid) {
  #pragma unroll
  for (int k = 0; k < N; ++k)
    for (int o = 32; o > 0; o >>= 1) v[k] += __shfl_down(v[k], o, 64);
  __syncthreads();
  if ((tid & 63) == 0) {
    const int w = tid >> 6;
    #pragma unroll
    for (int k = 0; k < N; ++k) sred[k*8 + w] = v[k];
  }
  __syncthreads();
  #pragma unroll
  for (int k = 0; k < N; ++k) {
    float s = sred[k*8 + 0];
    #pragma unroll
    for (int w = 1; w < 8; ++w) s += sred[k*8 + w];
    v[k] = s;
  }
  __syncthreads();
}

__global__ __launch_bounds__(TPB)
void toyac_kernel(KParams p) {
  const int g = blockIdx.x;
  const int tid = threadIdx.x;
  float* ws = p.ws;
  unsigned* bar = (unsigned*)p.ws;
  const int isOwner = (g < NOWN);
  const int og = (g >= NOWN && g < LEADER) ? (g - NOWN) : g;
  const int c0 = ROWS * ((g < NOWN) ? g : og);

  __shared__ float sBuf[8192];
  __shared__ float sH4[ROWS][HSS];   // helper hidden; alias sEv in dBulk
  __shared__ float sX[ROWS][EE];
  __shared__ float sP[ROWS][EE];
  __shared__ float sPE[ROWS][EE];
  __shared__ float sHv[HSS];         // P0b
  __shared__ float sMS[EE];
  __shared__ float sMS2[EE];
  __shared__ float sSE[EE];
  __shared__ float sP1[HPP];
  __shared__ float sD[ROWS];
  __shared__ float sR48[48];
  __shared__ float s8[8];
  __shared__ float sRed[16];
  __shared__ float sSm[40];

  float (*sEv)[MM] = (float(*)[MM])sH4;

  const int hq = (tid & 127) * 4;
  const int eg4 = tid >> 7;

  // ================= P0a =================
  if (isOwner) {
    const int e = tid & 127, r = tid >> 7, c = c0 + r;
    double dv = exp(-(double)(2*(e>>1)) * log(10000.0) / 128.0);
    double arg = (double)c * dv;
    float pev = ((e & 1) == 0) ? (float)sin(arg) : (float)cos(arg);
    sPE[r][e] = pev;
    float m0v = p.mem0[(size_t)c*EE + e] + pev;
    stA(ws + OFF_MP + (size_t)c*EE + e, m0v);
    sX[r][e] = m0v;
  } else if (g == LEADER) {
    for (int jj = tid; jj < HSS; jj += TPB) {
      float a0=0.f,a1=0.f,a2=0.f,a3=0.f,cb=0.f;
      for (int e = 0; e < EE; ++e) {
        float wv = p.Ws[(size_t)e*HSS + jj];
        a0 += p.Wemb[e]*wv; a1 += p.Wemb[EE+e]*wv;
        a2 += p.Wemb[2*EE+e]*wv; a3 += p.Wemb[3*EE+e]*wv;
        cb += p.bemb[e]*wv;
      }
      ws[OFF_CS + jj] = a0; ws[OFF_CS + HSS + jj] = a1;
      ws[OFF_CS + 2*HSS + jj] = a2; ws[OFF_CS + 3*HSS + jj] = a3;
      ws[OFF_CBS + jj] = cb;
    }
    if (tid < HPP) {
      int k = tid;
      float a0=0.f,a1=0.f,a2=0.f,a3=0.f,cb=0.f;
      for (int e = 0; e < EE; ++e) {
        float wv = p.Wp1[(size_t)e*HPP + k];
        a0 += p.Wemb[e]*wv; a1 += p.Wemb[EE+e]*wv;
        a2 += p.Wemb[2*EE+e]*wv; a3 += p.Wemb[3*EE+e]*wv;
        cb += p.bemb[e]*wv;
      }
      ws[OFF_CP + k] = a0; ws[OFF_CP + HPP + k] = a1;
      ws[OFF_CP + 2*HPP + k] = a2; ws[OFF_CP + 3*HPP + k] = a3;
      ws[OFF_CBP + k] = cb;
    }
  }

  // ================= P0b: per-step R0, W0 (striped over 129 blocks) =================
  for (int t = g; t < BSZ; t += NBLK) {
    __syncthreads();
    if (tid < EE) {
      const float* st = p.state + (size_t)t*4;
      sSE[tid] = st[0]*p.Wemb[tid] + st[1]*p.Wemb[EE+tid]
               + st[2]*p.Wemb[2*EE+tid] + st[3]*p.Wemb[3*EE+tid] + p.bemb[tid];
    }
    __syncthreads();
    { // reader score r0
      f4 a = {0.f,0.f,0.f,0.f};
      const float* base = p.Wr1 + (size_t)(eg4*32)*HSS + hq;
      for (int i = 0; i < 32; ++i)
        a += sSE[eg4*32 + i] * (*(const f4*)(base + (size_t)i*HSS));
      *(f4*)(sBuf + (size_t)eg4*HSS + hq) = a;
      __syncthreads();
      int h = tid;
      float hid = sBuf[h] + sBuf[HSS+h] + sBuf[2*HSS+h] + sBuf[3*HSS+h] + p.br1[h];
      float v = fmaxf(hid, 0.f) * p.Wr2[h];
      float sc = brs(v, s8, tid);
      if (tid == 0) stA(ws + OFF_R0 + t, sc + p.br2[0]);
      __syncthreads();
    }
    { // writer row0
      f4 a = {0.f,0.f,0.f,0.f};
      const float* base = p.Ww1 + (size_t)(eg4*32)*HSS + hq;
      for (int i = 0; i < 32; ++i)
        a += sSE[eg4*32 + i] * (*(const f4*)(base + (size_t)i*HSS));
      *(f4*)(sBuf + (size_t)eg4*HSS + hq) = a;
      __syncthreads();
      int h = tid;
      sHv[h] = fmaxf(sBuf[h] + sBuf[HSS+h] + sBuf[2*HSS+h] + sBuf[3*HSS+h] + p.bw1[h], 0.f);
      __syncthreads();
      const int cq = (tid & 63) * 4, hg = tid >> 6;
      f4 q = {0.f,0.f,0.f,0.f};
      const float* b2 = p.Ww2 + (size_t)(hg*64)*MM + cq;
      for (int i = 0; i < 64; ++i)
        q += sHv[hg*64 + i] * (*(const f4*)(b2 + (size_t)i*MM));
      *(f4*)(sBuf + (size_t)hg*MM + cq) = q;
      __syncthreads();
      if (tid < MM) {
        float s = 0.f;
        #pragma unroll
        for (int k = 0; k < 8; ++k) s += sBuf[(size_t)k*MM + tid];
        stA(ws + OFF_W0 + (size_t)t*MM + tid, s + p.bw2[tid]);
      }
      __syncthreads();
    }
  }

  // ---------- owner: stageA (full Wr1 pass) ----------
  auto stageA = [&](float* esSumOut) {
    {
      f4 a0={0.f,0.f,0.f,0.f},a1=a0,a2=a0,a3=a0;
      const float* base = p.Wr1 + (size_t)(eg4*32)*HSS + hq;
      for (int i = 0; i < 32; ++i) {
        f4 w = *(const f4*)(base + (size_t)i*HSS);
        int e = eg4*32 + i;
        a0 += sX[0][e]*w; a1 += sX[1][e]*w; a2 += sX[2][e]*w; a3 += sX[3][e]*w;
      }
      *(f4*)(sBuf + ((size_t)eg4*ROWS + 0)*HSS + hq) = a0;
      *(f4*)(sBuf + ((size_t)eg4*ROWS + 1)*HSS + hq) = a1;
      *(f4*)(sBuf + ((size_t)eg4*ROWS + 2)*HSS + hq) = a2;
      *(f4*)(sBuf + ((size_t)eg4*ROWS + 3)*HSS + hq) = a3;
    }
    __syncthreads();
    float sc[ROWS];
    {
      int h = tid;
      float b = p.br1[h], wr = p.Wr2[h];
      #pragma unroll
      for (int r = 0; r < ROWS; ++r) {
        float hid = sBuf[(0*ROWS+r)*HSS+h] + sBuf[(1*ROWS+r)*HSS+h]
                  + sBuf[(2*ROWS+r)*HSS+h] + sBuf[(3*ROWS+r)*HSS+h] + b;
        sc[r] = fmaxf(hid, 0.f) * wr;
      }
      brsN<ROWS>(sc, sR48, tid);
    }
    float es[ROWS];
    #pragma unroll
    for (int r = 0; r < ROWS; ++r) es[r] = expf(sc[r] + p.br2[0]);
    if (tid < EE) {
      float v = es[0]*sX[0][tid] + es[1]*sX[1][tid] + es[2]*sX[2][tid] + es[3]*sX[3][tid];
      stA(ws + OFF_EV + (size_t)g*EE + tid, v);
    }
    *esSumOut = es[0]+es[1]+es[2]+es[3];
  };

  auto ww2pass = [&](float* swdst) {
    const int cq = (tid & 63) * 4, hg = tid >> 6;
    f4 q0={0.f,0.f,0.f,0.f},q1=q0,q2=q0,q3=q0;
    const float* b2 = p.Ww2 + (size_t)(hg*64)*MM + cq;
    for (int i = 0; i < 64; ++i) {
      f4 w = *(const f4*)(b2 + (size_t)i*MM);
      int h = hg*64 + i;
      q0 += sH4[0][h]*w; q1 += sH4[1][h]*w; q2 += sH4[2][h]*w; q3 += sH4[3][h]*w;
    }
    *(f4*)(sBuf + ((size_t)hg*ROWS + 0)*MM + cq) = q0;
    *(f4*)(sBuf + ((size_t)hg*ROWS + 1)*MM + cq) = q1;
    *(f4*)(sBuf + ((size_t)hg*ROWS + 2)*MM + cq) = q2;
    *(f4*)(sBuf + ((size_t)hg*ROWS + 3)*MM + cq) = q3;
    __syncthreads();
    {
      const int col = tid & 255, rp = tid >> 8;
      #pragma unroll
      for (int rr = 0; rr < 2; ++rr) {
        int r = rp*2 + rr;
        float s = 0.f;
        #pragma unroll
        for (int k = 0; k < 8; ++k) s += sBuf[((size_t)k*ROWS + r)*MM + col];
        stA(swdst + (size_t)(c0 + r)*MM + col, s + p.bw2[col]);
      }
    }
  };

  auto stageC = [&](float* swdst) {
    {
      f4 a0={0.f,0.f,0.f,0.f},a1=a0,a2=a0,a3=a0;
      const float* base = p.Ww1 + (size_t)(eg4*32)*HSS + hq;
      for (int i = 0; i < 32; ++i) {
        f4 w = *(const f4*)(base + (size_t)i*HSS);
        int e = eg4*32 + i;
        a0 += sX[0][e]*w; a1 += sX[1][e]*w; a2 += sX[2][e]*w; a3 += sX[3][e]*w;
      }
      *(f4*)(sBuf + ((size_t)eg4*ROWS + 0)*HSS + hq) = a0;
      *(f4*)(sBuf + ((size_t)eg4*ROWS + 1)*HSS + hq) = a1;
      *(f4*)(sBuf + ((size_t)eg4*ROWS + 2)*HSS + hq) = a2;
      *(f4*)(sBuf + ((size_t)eg4*ROWS + 3)*HSS + hq) = a3;
    }
    __syncthreads();
    {
      int h = tid;
      float b = p.bw1[h];
      #pragma unroll
      for (int r = 0; r < ROWS; ++r)
        sH4[r][h] = fmaxf(sBuf[(0*ROWS+r)*HSS+h] + sBuf[(1*ROWS+r)*HSS+h]
                        + sBuf[(2*ROWS+r)*HSS+h] + sBuf[(3*ROWS+r)*HSS+h] + b, 0.f);
    }
    __syncthreads();
    ww2pass(swdst);
  };

  auto dBulkH = [&](int tt) {
    float* swc = ws + OFF_SW + (size_t)(tt&1)*MM*MM;
    float* mpc = ws + OFF_MP + (size_t)(tt&1)*MM*EE;
    float ex[ROWS] = {0.f,0.f,0.f,0.f};
    if (tid < MM) {
      f4 s = ldA4(swc + (size_t)tid*MM + c0);
      #pragma unroll
      for (int r = 0; r < ROWS; ++r) { ex[r] = expf(s[r]); sEv[r][tid] = ex[r]; }
    }
    brsN<ROWS>(ex, sR48, tid);
    if (tid == 0) { sD[0]=ex[0]; sD[1]=ex[1]; sD[2]=ex[2]; sD[3]=ex[3]; }
    {
      const int e4 = (tid & 31) * 4, rg = tid >> 5;
      f4 a0={0.f,0.f,0.f,0.f},a1=a0,a2=a0,a3=a0;
      const float* base = mpc + (size_t)(rg*16)*EE + e4;
      f4 vv[8];
      ldA4x8(base, EE, vv);
      #pragma unroll
      for (int i = 0; i < 8; ++i) {
        int r0 = rg*16 + i;
        a0 += sEv[0][r0]*vv[i]; a1 += sEv[1][r0]*vv[i];
        a2 += sEv[2][r0]*vv[i]; a3 += sEv[3][r0]*vv[i];
      }
      ldA4x8(base + 8*EE, EE, vv);
      #pragma unroll
      for (int i = 0; i < 8; ++i) {
        int r0 = rg*16 + 8 + i;
        a0 += sEv[0][r0]*vv[i]; a1 += sEv[1][r0]*vv[i];
        a2 += sEv[2][r0]*vv[i]; a3 += sEv[3][r0]*vv[i];
      }
      *(f4*)(sBuf + ((size_t)0*16 + rg)*EE + e4) = a0;
      *(f4*)(sBuf + ((size_t)1*16 + rg)*EE + e4) = a1;
      *(f4*)(sBuf + ((size_t)2*16 + rg)*EE + e4) = a2;
      *(f4*)(sBuf + ((size_t)3*16 + rg)*EE + e4) = a3;
    }
    __syncthreads();
    {
      const int e = tid & 127, r = tid >> 7;
      float s = 0.f;
      #pragma unroll
      for (int q = 0; q < 16; ++q) s += sBuf[((size_t)r*16 + q)*EE + e];
      stA(ws + OFF_BP + ((size_t)og*ROWS + r)*EE + e, s);
    }
  };

  // ================= main =================
  if (g == LEADER) {
    for (int t = 0; t < BSZ; ++t) {
      float er0 = expf(ldA(ws + OFF_R0 + t));
      float v = 0.f;
      if (tid < NOWN) {
        float* es = ws + OFF_ES + (size_t)((t&1)*NOWN + tid)*32;
        do { v = ldA(es); } while (v == 0.f);
        stA(es, 0.f);
      }
      float invd = 1.f / (er0 + brs(v, s8, tid));
      {
        const int e4 = (tid & 31) * 4, qg = tid >> 5;
        f4 vv[4];
        ldA4x4(ws + OFF_EV + (size_t)(qg*4)*EE + e4, EE, vv);
        f4 acc = vv[0]+vv[1]+vv[2]+vv[3];
        *(f4*)(sBuf + (size_t)qg*EE + e4) = acc;
      }
      __syncthreads();
      {
        const float* st = p.state + (size_t)t*4;
        const float s0 = st[0], s1 = st[1], s2 = st[2], s3 = st[3];
        if (tid < EE) {
          float se = s0*p.Wemb[tid] + s1*p.Wemb[EE+tid]
                   + s2*p.Wemb[2*EE+tid] + s3*p.Wemb[3*EE+tid] + p.bemb[tid];
          float s = 0.f;
          #pragma unroll
          for (int q = 0; q < 16; ++q) s += sBuf[(size_t)q*EE + tid];
          sMS[tid] = (er0*se + s) * invd;
        }
        __syncthreads();
        { // trunk hidden (streamed Ws mem-half)
          f4 a = {0.f,0.f,0.f,0.f};
          const float* base = p.Ws + (size_t)(EE + eg4*32)*HSS + hq;
          for (int i = 0; i < 32; ++i)
            a += sMS[eg4*32 + i] * (*(const f4*)(base + (size_t)i*HSS));
          *(f4*)(sBuf + (size_t)eg4*HSS + hq) = a;
        }
        __syncthreads();
        float hv;
        {
          const float* cs = ws + OFF_CS;
          float sh0 = s0*cs[tid] + s1*cs[HSS+tid] + s2*cs[2*HSS+tid] + s3*cs[3*HSS+tid]
                    + ws[OFF_CBS + tid];
          hv = fmaxf(sBuf[tid] + sBuf[HSS+tid] + sBuf[2*HSS+tid] + sBuf[3*HSS+tid]
                     + sh0 + p.bs[tid], 0.f);
        }
        __syncthreads();
        {
          float pa[6];
          #pragma unroll
          for (int aa = 0; aa < 5; ++aa) pa[aa] = hv * p.Wa[(size_t)tid*5 + aa];
          pa[5] = hv * p.Wc[tid];
          brsN<6>(pa, sR48, tid);
          if (tid == 0) {
            float l0=pa[0]+p.ba[0], l1=pa[1]+p.ba[1], l2=pa[2]+p.ba[2];
            float l3=pa[3]+p.ba[3], l4=pa[4]+p.ba[4];
            float mx = fmaxf(fmaxf(fmaxf(l0,l1),fmaxf(l2,l3)), l4);
            float e0=expf(l0-mx),e1=expf(l1-mx),e2=expf(l2-mx),e3=expf(l3-mx),e4v=expf(l4-mx);
            float is = 1.f/(e0+e1+e2+e3+e4v);
            float p0=e0*is,p1=e1*is,p2=e2*is,p3=e3*is,p4=e4v*is;
            p.out[(size_t)t*5+0]=p0; p.out[(size_t)t*5+1]=p1; p.out[(size_t)t*5+2]=p2;
            p.out[(size_t)t*5+3]=p3; p.out[(size_t)t*5+4]=p4;
            float val = pa[5] + p.bc[0];
            p.out[(size_t)BSZ*5 + t] = val;
            sSm[1]=p0; sSm[2]=p1; sSm[3]=p2; sSm[4]=p3; sSm[5]=p4; sSm[6]=val;
          }
          __syncthreads();
        }
        { // p1 stream
          const int cq = (tid & 63) * 4, eg8 = tid >> 6;
          f4 a = {0.f,0.f,0.f,0.f};
          const float* base = p.Wp1 + (size_t)(EE + eg8*16)*HPP + cq;
          for (int i = 0; i < 16; ++i)
            a += sMS[eg8*16 + i] * (*(const f4*)(base + (size_t)i*HPP));
          *(f4*)(sBuf + (size_t)eg8*HPP + cq) = a;
        }
        __syncthreads();
        if (tid < HPP) {
          const float* cp = ws + OFF_CP;
          float acc = s0*cp[tid] + s1*cp[HPP+tid] + s2*cp[2*HPP+tid] + s3*cp[3*HPP+tid]
                    + ws[OFF_CBP + tid] + p.bp1[tid];
          #pragma unroll
          for (int q = 0; q < 8; ++q) acc += sBuf[(size_t)q*HPP + tid];
          #pragma unroll
          for (int aa = 0; aa < 5; ++aa) acc += sSm[1+aa] * p.Wp1[(size_t)(2*EE+aa)*HPP + tid];
          acc += sSm[6] * p.Wp1[(size_t)(2*EE+5)*HPP + tid];
          sP1[tid] = fmaxf(acc, 0.f);
        }
        __syncthreads();
        { // ms2 stream
          const int cq = (tid & 31) * 4, kg = tid >> 5;
          f4 a = {0.f,0.f,0.f,0.f};
          const float* base = p.Wp2 + (size_t)(kg*16)*EE + cq;
          for (int i = 0; i < 16; ++i)
            a += sP1[kg*16 + i] * (*(const f4*)(base + (size_t)i*EE));
          *(f4*)(sBuf + (size_t)kg*EE + cq) = a;
        }
        __syncthreads();
        if (tid < EE) {
          float s = sBuf[tid] + sBuf[EE+tid] + sBuf[2*EE+tid] + sBuf[3*EE+tid];
          float m = s + p.bp2[tid];
          sMS2[tid] = m;                      // keep local copy for hms
          stA(ws + OFF_MS2 + tid, m);
        }
      }
      drainSync();
      if (tid == 0) stAu(&bar[MSQ_IDX], (unsigned)(t+1));
      __syncthreads();
      // ---- hms in leader's idle window (identical summation order to R10 owner) ----
      {
        f4 a = {0.f,0.f,0.f,0.f};
        const float* base = p.Ww1 + (size_t)(eg4*32)*HSS + hq;
        for (int i = 0; i < 32; ++i)
          a += sMS2[eg4*32 + i] * (*(const f4*)(base + (size_t)i*HSS));
        *(f4*)(sBuf + (size_t)eg4*HSS + hq) = a;
      }
      __syncthreads();
      stA(ws + OFF_HMS + tid,
          fmaxf(sBuf[tid] + sBuf[HSS+tid] + sBuf[2*HSS+tid] + sBuf[3*HSS+tid]
                + p.bw1[tid], 0.f));
      drainSync();
      if (tid == 0) stAu(&bar[HMSQ_IDX], (unsigned)(t+1));
    }
  } else if (isOwner) {
    // -------- OWNER --------
    const f4 wcol = *(const f4*)(p.Ww2 + (size_t)tid*MM + c0);
    drainSync();
    if (tid == 0) stAu(&bar[ROWQ(g)], 1u);     // rows(0) ready
    float esSum;
    stageA(&esSum);
    drainSync();
    if (tid == 0) stA(ws + OFF_ES + (size_t)g*32, esSum);   // ES(0), parity 0

    for (int t = 0; t < BSZ-1; ++t) {
      // flag-independent precompute
      if (tid < EE) {
        const float* st = p.state + (size_t)t*4;
        sSE[tid] = st[0]*p.Wemb[tid] + st[1]*p.Wemb[EE+tid]
                 + st[2]*p.Wemb[2*EE+tid] + st[3]*p.Wemb[3*EE+tid] + p.bemb[tid];
      }
      if (tid == 0) {
        f4 w0 = ldA4(ws + OFF_W0 + (size_t)t*MM + c0);
        sSm[8]=expf(w0.x); sSm[9]=expf(w0.y); sSm[10]=expf(w0.z); sSm[11]=expf(w0.w);
      }
      // wait ms2(t) — busy poll
      if (tid == 0) { while (ldAu(&bar[MSQ_IDX]) < (unsigned)(t+1)) {} }
      __syncthreads();
      if (tid < EE) sMS2[tid] = ldA(ws + OFF_MS2 + tid);
      // BD poll (value-as-flag) + consume + reset
      if (tid == 0) {
        float* bd = ws + OFF_BD + (size_t)g*32;
        float x,y,z,w;
        do { x=ldA(bd); y=ldA(bd+1); z=ldA(bd+2); w=ldA(bd+3); }
        while (x==0.f || y==0.f || z==0.f || w==0.f);
        sD[0]=x; sD[1]=y; sD[2]=z; sD[3]=w;
        stA(bd,0.f); stA(bd+1,0.f); stA(bd+2,0.f); stA(bd+3,0.f);
      }
      __syncthreads();
      { // BP read
        const int e = tid & 127, r = tid >> 7;
        sP[r][e] = ldA(ws + OFF_BP + ((size_t)g*ROWS + r)*EE + e);
      }
      // wait leader's hms(t), read own h value
      if (tid == 0) { while (ldAu(&bar[HMSQ_IDX]) < (unsigned)(t+1)) {} }
      __syncthreads();
      float hm = ldA(ws + OFF_HMS + tid);
      float swv[ROWS] = { hm*wcol.x, hm*wcol.y, hm*wcol.z, hm*wcol.w };
      brsN<ROWS>(swv, sR48, tid);
      // dFinish
      {
        const int e = tid & 127, r = tid >> 7;
        float ew1 = expf(swv[r] + p.bw2[c0+r]);
        float ew0 = sSm[8+r];
        float inv = 1.f / (sD[r] + ew0 + ew1);
        float x = (sP[r][e] + ew0*sSE[e] + ew1*sMS2[e]) * inv;
        float mn = x, mx = x;
        #pragma unroll
        for (int o = 1; o < 64; o <<= 1) {
          mn = fminf(mn, __shfl_xor(mn, o, 64));
          mx = fmaxf(mx, __shfl_xor(mx, o, 64));
        }
        if ((tid & 63) == 0) { sRed[(tid>>6)*2] = mn; sRed[(tid>>6)*2+1] = mx; }
        __syncthreads();
        mn = fminf(sRed[4*r], sRed[4*r+2]);
        mx = fmaxf(sRed[4*r+1], sRed[4*r+3]);
        float k = 1.f / (mx - mn);
        float xr = (x - mn) * k + sPE[r][e];
        stA(ws + OFF_MP + (size_t)((t+1)&1)*MM*EE + (size_t)(c0+r)*EE + e, xr);
        sX[r][e] = xr;
      }
      drainSync();
      if (tid == 0) stAu(&bar[ROWQ(g)], (unsigned)(t+2));  // rows(t+1)
      // stageA(t+1)
      stageA(&esSum);
      drainSync();
      if (tid == 0) stA(ws + OFF_ES + (size_t)(((t+1)&1)*NOWN + g)*32, esSum);
    }
  } else {
    // -------- HELPER --------
    for (int t = 0; t < BSZ-1; ++t) {
      if (tid == 0) {
        while (ldAu(&bar[ROWQ(og)]) < (unsigned)(t+1)) __builtin_amdgcn_s_sleep(1);
      }
      __syncthreads();
      {
        const int e = tid & 127, r = tid >> 7;
        sX[r][e] = ldA(ws + OFF_MP + (size_t)(t&1)*MM*EE + (size_t)(c0+r)*EE + e);
      }
      __syncthreads();
      stageC(ws + OFF_SW + (size_t)(t&1)*MM*MM);
      drainSync();
      if (tid == 0) stAu(&bar[SCQ(og)], (unsigned)(t+1));
      if (tid < 64) {
        while (ldAu(&bar[SCQ(tid)]) < (unsigned)(t+1)) __builtin_amdgcn_s_sleep(1);
      } else if (tid < 128) {
        while (ldAu(&bar[ROWQ(tid-64)]) < (unsigned)(t+1)) __builtin_amdgcn_s_sleep(1);
      }
      __syncthreads();
      dBulkH(t);
      drainSync();
      if (tid == 0) {
        float* bd = ws + OFF_BD + (size_t)og*32;
        stA(bd,   sD[0]); stA(bd+1, sD[1]);
        stA(bd+2, sD[2]); stA(bd+3, sD[3]);
      }
    }
  }
}

extern "C" void kernel_launch(void* const* d_in, const int* in_sizes, int n_in,
                              void* d_out, int out_size, void* d_ws, size_t ws_size,
                              hipStream_t stream) {
  hipMemsetAsync(d_ws, 0, OFF_PE * 4, stream);
  KParams kp;
  kp.state = (const float*)d_in[0];
  kp.mem0  = (const float*)d_in[1];
  kp.Wemb  = (const float*)d_in[2];
  kp.bemb  = (const float*)d_in[3];
  kp.Wr1   = (const float*)d_in[4];
  kp.br1   = (const float*)d_in[5];
  kp.Wr2   = (const float*)d_in[6];
  kp.br2   = (const float*)d_in[7];
  kp.Ww1   = (const float*)d_in[8];
  kp.bw1   = (const float*)d_in[9];
  kp.Ww2   = (const float*)d_in[10];
  kp.bw2   = (const float*)d_in[11];
  kp.Ws    = (const float*)d_in[12];
  kp.bs    = (const float*)d_in[13];
  kp.Wa    = (const float*)d_in[14];
  kp.ba    = (const float*)d_in[15];
  kp.Wc    = (const float*)d_in[16];
  kp.bc    = (const float*)d_in[17];
  kp.Wp1   = (const float*)d_in[18];
  kp.bp1   = (const float*)d_in[19];
  kp.Wp2   = (const float*)d_in[20];
  kp.bp2   = (const float*)d_in[21];
  kp.out   = (float*)d_out;
  kp.ws    = (float*)d_ws;
  toyac_kernel<<<dim3(NBLK), dim3(TPB), 0, stream>>>(kp);
}